// Round 9
// baseline (118.291 us; speedup 1.0000x reference)
//
#include <hip/hip_runtime.h>
#include <stdint.h>

// Problem: B=2, T=2048, C=1024, H=16, HD=64. M = B*T = 4096, 3C = 3072.
// Geo bias folded into Q:  q~[d] = q[d]*SCALE + hs*(q[:8]·dir)*dir[d] (d<8)
// log2(e) additionally folded into Q~ so softmax uses exp2 directly.
// Softmax is MAX-FREE: P = exp2(S') directly (S' provably < ~25 << 127).

typedef float f32x4 __attribute__((ext_vector_type(4)));
typedef unsigned short u16x8 __attribute__((ext_vector_type(8)));
typedef unsigned short u16x4 __attribute__((ext_vector_type(4)));
typedef unsigned int u32x2 __attribute__((ext_vector_type(2)));
typedef __bf16 bf16x8 __attribute__((ext_vector_type(8)));

static __device__ __forceinline__ unsigned short f2bf(float f) {
  unsigned u = __float_as_uint(f);
  u += 0x7FFFu + ((u >> 16) & 1u);
  return (unsigned short)(u >> 16);
}
static __device__ __forceinline__ float bf2f(unsigned short s) {
  return __uint_as_float(((unsigned)s) << 16);
}
static __device__ __forceinline__ f32x4 mfma16(u16x8 a, u16x8 b, f32x4 c) {
  return __builtin_amdgcn_mfma_f32_16x16x32_bf16(
      __builtin_bit_cast(bf16x8, a), __builtin_bit_cast(bf16x8, b), c, 0, 0, 0);
}
static __device__ __forceinline__ unsigned cvtpk(float lo, float hi) {
  unsigned d;
  asm("v_cvt_pk_bf16_f32 %0, %1, %2" : "=v"(d) : "v"(lo), "v"(hi));
  return d;
}

#define GLD16(gp, lp) __builtin_amdgcn_global_load_lds( \
    (const __attribute__((address_space(1))) unsigned int*)(gp), \
    (__attribute__((address_space(3))) unsigned int*)(lp), 16, 0, 0)

// ---------------- fused prep: cast x->bf16 ; transpose+cast wqkv, wout ----------------
__global__ __launch_bounds__(256) void k_prep(const float* __restrict__ x,
                                              const float* __restrict__ wqkv,
                                              const float* __restrict__ wout,
                                              unsigned short* __restrict__ xb,
                                              unsigned short* __restrict__ wqkvT,
                                              unsigned short* __restrict__ woutT) {
  __shared__ float t[64][65];
  const int bid = blockIdx.x;
  if (bid < 4096) {
    int i = bid * 256 + threadIdx.x;
    f32x4 v = *(const f32x4*)(x + (size_t)i * 4);
    u16x4 o;
#pragma unroll
    for (int j = 0; j < 4; ++j) o[j] = f2bf(v[j]);
    *(u16x4*)(xb + (size_t)i * 4) = o;
    return;
  }
  const float* in;
  unsigned short* out;
  int Cc, bx, by;
  if (bid < 4864) {
    int tt = bid - 4096;
    in = wqkv; out = wqkvT; Cc = 3072;
    bx = tt % 48; by = tt / 48;
  } else {
    int tt = bid - 4864;
    in = wout; out = woutT; Cc = 1024;
    bx = tt & 15; by = tt >> 4;
  }
  const int R = 1024;
  int tr = by * 64, tc = bx * 64;
  int tx = threadIdx.x & 15, ty = threadIdx.x >> 4;
#pragma unroll
  for (int i = 0; i < 4; ++i) {
    int rr = ty + i * 16;
    f32x4 v = *(const f32x4*)(in + (size_t)(tr + rr) * Cc + tc + tx * 4);
#pragma unroll
    for (int j = 0; j < 4; ++j) t[rr][tx * 4 + j] = v[j];
  }
  __syncthreads();
#pragma unroll
  for (int i = 0; i < 4; ++i) {
    int cc = ty + i * 16;
    int rr = tx * 4;
    u16x4 o;
#pragma unroll
    for (int j = 0; j < 4; ++j) o[j] = f2bf(t[rr + j][cc]);
    *(u16x4*)(out + (size_t)(tc + cc) * R + tr + rr) = o;
  }
}

// ---------------- QKV GEMM: 256x256 tile, BK=32, 8 waves, 4-deep LDS ring ----------------
// C[m][n] = sum_k A[m][k]*Bt[n][k], M=4096 N=3072 K=1024. Grid 192 blocks (16x12),
// 1 block/CU. Per step t: read buf[t&3], stage tile t+3 into buf[(t-1)&3] (freed
// at prev step's trailing barrier -> race-free by construction). Two phases/step,
// each {ds_read frags; 2 GLD; barrier; lgkmcnt(0); 16 MFMA; barrier}; counted
// vmcnt(8) at step end (T3+T4 discipline), drains 4->0 only in the last steps.
__global__ __launch_bounds__(512, 1) void k_gemm_qkv(const unsigned short* __restrict__ A,
                                                     const unsigned short* __restrict__ Bt,
                                                     unsigned short* __restrict__ qo,
                                                     unsigned short* __restrict__ ko,
                                                     unsigned short* __restrict__ vTo) {
  __shared__ unsigned short lA[4][256 * 32];   // 64 KB
  __shared__ unsigned short lB[4][256 * 32];   // 64 KB
  const int tid = threadIdx.x;
  const int lane = tid & 63, wid = tid >> 6;   // 8 waves
  const int wr = wid >> 2, wc = wid & 3;       // 2 x 4 wave grid
  const int r = lane & 15, g = lane >> 4;
  // XCD-chunked swizzle (192 % 8 == 0 -> bijective): 24 consecutive per XCD.
  const int bid0 = blockIdx.x;
  const int swz = (bid0 & 7) * 24 + (bid0 >> 3);
  const int mbase = (swz / 12) * 256, nbase = (swz % 12) * 256;

  auto STAGE_A = [&](int buf, int kt) {
#pragma unroll
    for (int p = 0; p < 2; ++p) {
      int L = p * 8192 + tid * 16;       // byte offset in 16KB A-tile [256][32]bf16
      int row = L >> 6, cb = (L >> 4) & 3;
      GLD16(A + (size_t)(mbase + row) * 1024 + kt * 32 + cb * 8, lA[buf] + (L >> 1));
    }
  };
  auto STAGE_B = [&](int buf, int kt) {
#pragma unroll
    for (int p = 0; p < 2; ++p) {
      int L = p * 8192 + tid * 16;
      int row = L >> 6, cb = (L >> 4) & 3;
      GLD16(Bt + (size_t)(nbase + row) * 1024 + kt * 32 + cb * 8, lB[buf] + (L >> 1));
    }
  };

  f32x4 acc[8][4] = {};

  // prologue: tiles 0,1,2 into bufs 0,1,2 (12 loads); wait tile 0 (8 newest allowed)
  STAGE_A(0, 0); STAGE_B(0, 0);
  STAGE_A(1, 1); STAGE_B(1, 1);
  STAGE_A(2, 2); STAGE_B(2, 2);
  asm volatile("s_waitcnt vmcnt(8)" ::: "memory");
  __builtin_amdgcn_sched_barrier(0);
  __builtin_amdgcn_s_barrier();

  for (int t = 0; t < 32; ++t) {
    const int buf = t & 3;
    const int nbuf = (t + 3) & 3;    // == (t-1)&3: freed at prev step's last barrier
    const unsigned short* pA = lA[buf];
    const unsigned short* pB = lB[buf];

    // ---- phase 0: B frags (kept both phases) + A mf0-3; stage A(t+3)
    u16x8 bf[4], af[4];
#pragma unroll
    for (int nf = 0; nf < 4; ++nf)
      bf[nf] = *(const u16x8*)(pB + (wc * 64 + nf * 16 + r) * 32 + g * 8);
#pragma unroll
    for (int mf = 0; mf < 4; ++mf)
      af[mf] = *(const u16x8*)(pA + (wr * 128 + mf * 16 + r) * 32 + g * 8);
    if (t + 3 < 32) STAGE_A(nbuf, t + 3);
    __builtin_amdgcn_s_barrier();
    asm volatile("s_waitcnt lgkmcnt(0)" ::: "memory");
    __builtin_amdgcn_sched_barrier(0);
    __builtin_amdgcn_s_setprio(1);
#pragma unroll
    for (int mf = 0; mf < 4; ++mf)
#pragma unroll
      for (int nf = 0; nf < 4; ++nf) acc[mf][nf] = mfma16(af[mf], bf[nf], acc[mf][nf]);
    __builtin_amdgcn_s_setprio(0);
    __builtin_amdgcn_s_barrier();

    // ---- phase 1: A mf4-7; stage B(t+3)
#pragma unroll
    for (int mf = 0; mf < 4; ++mf)
      af[mf] = *(const u16x8*)(pA + (wr * 128 + (mf + 4) * 16 + r) * 32 + g * 8);
    if (t + 3 < 32) STAGE_B(nbuf, t + 3);
    __builtin_amdgcn_s_barrier();
    asm volatile("s_waitcnt lgkmcnt(0)" ::: "memory");
    __builtin_amdgcn_sched_barrier(0);
    __builtin_amdgcn_s_setprio(1);
#pragma unroll
    for (int mf = 0; mf < 4; ++mf)
#pragma unroll
      for (int nf = 0; nf < 4; ++nf) acc[mf + 4][nf] = mfma16(af[mf], bf[nf], acc[mf + 4][nf]);
    __builtin_amdgcn_s_setprio(0);

    // step end: ensure tile t+1 landed; keep t+2/t+3 loads in flight (counted).
    if (t < 29) {
      asm volatile("s_waitcnt vmcnt(8)" ::: "memory");
    } else if (t == 29) {
      asm volatile("s_waitcnt vmcnt(4)" ::: "memory");
    } else if (t == 30) {
      asm volatile("s_waitcnt vmcnt(0)" ::: "memory");
    }
    __builtin_amdgcn_sched_barrier(0);
    __builtin_amdgcn_s_barrier();
  }

  // epilogue: scatter Q,K as [BH][T][64] bf16 and V^T as [BH][64][T] bf16
#pragma unroll
  for (int mf = 0; mf < 8; ++mf) {
#pragma unroll
    for (int nf = 0; nf < 4; ++nf) {
      int ng = nbase + wc * 64 + nf * 16 + r;
      int m0 = mbase + wr * 128 + mf * 16 + g * 4;
      int sec = ng >> 10, rem = ng & 1023, hh = rem >> 6, d = rem & 63;
      int b = m0 >> 11, t0 = m0 & 2047;
      size_t bh = (size_t)(b * 16 + hh);
      if (sec == 2) {
        u16x4 o;
#pragma unroll
        for (int e = 0; e < 4; ++e) o[e] = f2bf(acc[mf][nf][e]);
        *(u16x4*)(vTo + (bh * 64 + d) * 2048 + t0) = o;  // V^T: [bh][d][t]
      } else {
        unsigned short* dst = (sec == 0 ? qo : ko);
#pragma unroll
        for (int e = 0; e < 4; ++e)
          dst[(bh * 2048 + t0 + e) * 64 + d] = f2bf(acc[mf][nf][e]);
      }
    }
  }
}

// ---------------- projection GEMM: 128x128 tile (m97 structure) ----------------
__global__ __launch_bounds__(256) void k_gemm_out(const unsigned short* __restrict__ A,
                                                  const unsigned short* __restrict__ Bt,
                                                  float* __restrict__ fo) {
  __shared__ unsigned short lA[128 * 32];
  __shared__ unsigned short lB[128 * 32];
  const int tid = threadIdx.x;
  const int lane = tid & 63, wid = tid >> 6;
  const int wr = wid >> 1, wc = wid & 1;
  const int r = lane & 15, g = lane >> 4;
  const int mbase = blockIdx.y * 128;
  const int nbase = blockIdx.x * 128;

  f32x4 acc[4][4] = {};

  for (int kt = 0; kt < 32; ++kt) {
    __syncthreads();
#pragma unroll
    for (int p = 0; p < 2; ++p) {
      int L = p * 4096 + tid * 16;
      int row = L >> 6;
      int blk = (L >> 4) & 3;
      GLD16(A + (size_t)(mbase + row) * 1024 + kt * 32 + blk * 8, lA + (L >> 1));
      GLD16(Bt + (size_t)(nbase + row) * 1024 + kt * 32 + blk * 8, lB + (L >> 1));
    }
    __syncthreads();
    u16x8 af[4], bfv[4];
#pragma unroll
    for (int m = 0; m < 4; ++m)
      af[m] = *(const u16x8*)(lA + (wr * 64 + m * 16 + r) * 32 + g * 8);
#pragma unroll
    for (int n = 0; n < 4; ++n)
      bfv[n] = *(const u16x8*)(lB + (wc * 64 + n * 16 + r) * 32 + g * 8);
#pragma unroll
    for (int m = 0; m < 4; ++m)
#pragma unroll
      for (int n = 0; n < 4; ++n) acc[m][n] = mfma16(af[m], bfv[n], acc[m][n]);
  }

#pragma unroll
  for (int m = 0; m < 4; ++m)
#pragma unroll
    for (int n = 0; n < 4; ++n) {
      int ng = nbase + wc * 64 + n * 16 + r;
      int m0 = mbase + wr * 64 + m * 16 + g * 4;
#pragma unroll
      for (int e = 0; e < 4; ++e)
        fo[(size_t)(m0 + e) * 1024 + ng] = acc[m][n][e];
    }
}

// ---------------- causal flash attention, head_dim 64, folded E8 bias ----------------
// R5/R8 structure: 1024 blocks x 4 waves, 64 q-rows each, 40KB LDS -> 4 blocks/CU.
// Decode puts a = {j, 31-j, 8+j, 23-j} per CU (work sum 66). Counted-vmcnt
// double-buffer; max-free straight-line softmax (P = exp2(S'), lane-partial l).
__global__ __launch_bounds__(256) void k_attn(const unsigned short* __restrict__ qb,
                                              const unsigned short* __restrict__ kb,
                                              const unsigned short* __restrict__ vTb,
                                              const float* __restrict__ hsc,
                                              const float* __restrict__ hdir,
                                              unsigned short* __restrict__ o2) {
  __shared__ unsigned short lK[2][64 * 64];
  __shared__ unsigned short lV[2][64 * 64];
  __shared__ unsigned short lP[4][16 * 64];

  const int tid = threadIdx.x, lane = tid & 63, wid = tid >> 6;
  const int r = lane & 15, g = lane >> 4;
  const int bid = blockIdx.x;
  const int u = bid & 255, kq = bid >> 8;
  const int bh = u & 31, j = u >> 5;
  const int a = (kq == 0) ? j : (kq == 1) ? (31 - j) : (kq == 2) ? (8 + j) : (23 - j);
  const int nk = a + 1;
  const int qbase = a * 64;
  const int h = bh & 15, bi = bh >> 4;

  const size_t kbase = (size_t)bh * (2048 * 64);
  const size_t vbase = (size_t)bh * (64 * 2048);

  auto STAGE = [&](int buf, int kt) {
    unsigned short* dK = (unsigned short*)lK[buf];
    unsigned short* dV = (unsigned short*)lV[buf];
#pragma unroll
    for (int p = 0; p < 2; ++p) {
      int L = p * 4096 + tid * 16;
      int row = L >> 7;
      int cb = (L >> 4) & 7;
      int cbg = cb ^ (row & 7);
      GLD16(kb + kbase + (size_t)(kt * 64 + row) * 64 + cbg * 8, dK + (L >> 1));
      GLD16(vTb + vbase + (size_t)row * 2048 + kt * 64 + cbg * 8, dV + (L >> 1));
    }
  };

  STAGE(0, 0);

  const float LOG2E = 1.44269504088896f;
  const float hs = hsc[h];
  float dir8[8];
#pragma unroll
  for (int j2 = 0; j2 < 8; ++j2) dir8[j2] = hdir[h * 8 + j2];

  u16x8 qc0, qc1;
  {
    const unsigned short* qrow = qb + ((size_t)bh * 2048 + qbase + wid * 16 + r) * 64;
    float proj = 0.f;
    u16x8 qv = *(const u16x8*)qrow;
#pragma unroll
    for (int j2 = 0; j2 < 8; ++j2) proj += bf2f(qv[j2]) * dir8[j2];
#pragma unroll
    for (int s = 0; s < 2; ++s) {
      u16x8 raw = *(const u16x8*)(qrow + s * 32 + g * 8);
      u16x8 ov;
#pragma unroll
      for (int j2 = 0; j2 < 8; ++j2) {
        float v = bf2f(raw[j2]) * (0.125f * LOG2E);
        if (s == 0 && g == 0) v += (hs * LOG2E) * proj * dir8[j2];
        ov[j2] = f2bf(v);
      }
      if (s == 0) qc0 = ov; else qc1 = ov;
    }
  }

  f32x4 accO[4] = {};
  float lp = 0.f;
  unsigned short* pw = &lP[wid][0];
  const int swz = (r & 7) << 4;
  const int qq = qbase + wid * 16 + r;

  for (int kt = 0; kt < nk; ++kt) {
    asm volatile("s_waitcnt lgkmcnt(0)" ::: "memory");
    __builtin_amdgcn_sched_barrier(0);
    __builtin_amdgcn_s_barrier();
    __builtin_amdgcn_sched_barrier(0);

    if (kt + 1 < nk) STAGE((kt + 1) & 1, kt + 1);

    if (kt + 1 < nk) {
      asm volatile("s_waitcnt vmcnt(4)" ::: "memory");
    } else {
      asm volatile("s_waitcnt vmcnt(0)" ::: "memory");
    }
    __builtin_amdgcn_sched_barrier(0);
    __builtin_amdgcn_s_barrier();
    __builtin_amdgcn_sched_barrier(0);

    const char* lKc = (const char*)lK[kt & 1];
    const char* lVc = (const char*)lV[kt & 1];

    f32x4 accS[4];
    __builtin_amdgcn_s_setprio(1);
#pragma unroll
    for (int ct = 0; ct < 4; ++ct) {
      f32x4 s4 = {0.f, 0.f, 0.f, 0.f};
      int krow = ct * 16 + r;
      int sw = (krow & 7) << 4;
      u16x8 kf0 = *(const u16x8*)(lKc + krow * 128 + ((g * 16) ^ sw));
      u16x8 kf1 = *(const u16x8*)(lKc + krow * 128 + ((64 + g * 16) ^ sw));
      s4 = mfma16(kf0, qc0, s4);
      s4 = mfma16(kf1, qc1, s4);
      accS[ct] = s4;
    }
    __builtin_amdgcn_s_setprio(0);

    if (kt == nk - 1) {
#pragma unroll
      for (int ct = 0; ct < 4; ++ct)
#pragma unroll
        for (int e = 0; e < 4; ++e) {
          int kk = kt * 64 + ct * 16 + g * 4 + e;
          if (kk > qq) accS[ct][e] = -1e30f;
        }
    }

    float p[4][4];
#pragma unroll
    for (int ct = 0; ct < 4; ++ct)
#pragma unroll
      for (int e = 0; e < 4; ++e) p[ct][e] = exp2f(accS[ct][e]);
#pragma unroll
    for (int ct = 0; ct < 4; ++ct)
      lp += (p[ct][0] + p[ct][1]) + (p[ct][2] + p[ct][3]);

#pragma unroll
    for (int ct = 0; ct < 4; ++ct) {
      u32x2 w;
      w[0] = cvtpk(p[ct][0], p[ct][1]);
      w[1] = cvtpk(p[ct][2], p[ct][3]);
      *(u32x2*)((char*)pw + r * 128 + ((ct * 32 + g * 8) ^ swz)) = w;
    }
    asm volatile("s_waitcnt lgkmcnt(0)" ::: "memory");
    __builtin_amdgcn_sched_barrier(0);

    __builtin_amdgcn_s_setprio(1);
#pragma unroll
    for (int s = 0; s < 2; ++s) {
      u16x8 pa = *(const u16x8*)((const char*)pw + r * 128 + ((s * 64 + g * 16) ^ swz));
#pragma unroll
      for (int dt = 0; dt < 4; ++dt) {
        int dd = dt * 16 + r;
        u16x8 vf = *(const u16x8*)(lVc + dd * 128 + ((s * 64 + g * 16) ^ ((dd & 7) << 4)));
        accO[dt] = mfma16(vf, pa, accO[dt]);
      }
    }
    __builtin_amdgcn_s_setprio(0);
  }

  lp += __shfl_xor(lp, 16, 64);
  lp += __shfl_xor(lp, 32, 64);
  float inv = 1.f / lp;
#pragma unroll
  for (int dt = 0; dt < 4; ++dt) {
    u16x4 o;
#pragma unroll
    for (int e = 0; e < 4; ++e) o[e] = f2bf(accO[dt][e] * inv);
    *(u16x4*)(o2 + ((size_t)(bi * 2048 + qq)) * 1024 + h * 64 + dt * 16 + g * 4) = o;
  }
}

extern "C" void kernel_launch(void* const* d_in, const int* in_sizes, int n_in,
                              void* d_out, int out_size, void* d_ws, size_t ws_size,
                              hipStream_t stream) {
  const float* x    = (const float*)d_in[0];
  const float* wqkv = (const float*)d_in[1];
  const float* wout = (const float*)d_in[2];
  const float* hsc  = (const float*)d_in[3];
  const float* hdir = (const float*)d_in[4];
  float* outp = (float*)d_out;

  char* ws = (char*)d_ws;
  unsigned short* xb    = (unsigned short*)(ws + 0);         //  8 MB  [4096][1024]
  unsigned short* wqkvT = (unsigned short*)(ws + 8388608);   //  6 MB  [3072][1024]
  unsigned short* woutT = (unsigned short*)(ws + 14680064);  //  2 MB  [1024][1024]
  unsigned short* qb    = (unsigned short*)(ws + 16777216);  //  8 MB  [32][2048][64]
  unsigned short* kb    = (unsigned short*)(ws + 25165824);  //  8 MB  [32][2048][64]
  unsigned short* vT    = (unsigned short*)(ws + 33554432);  //  8 MB  [32][64][2048]
  unsigned short* x2b   = (unsigned short*)(ws + 41943040);  //  8 MB  [4096][1024]
  if (ws_size < 50331648u) return;

  k_prep<<<5120, 256, 0, stream>>>(x, wqkv, wout, xb, wqkvT, woutT);
  k_gemm_qkv<<<192, 512, 0, stream>>>(xb, wqkvT, qb, kb, vT);
  k_attn<<<dim3(1024), 256, 0, stream>>>(qb, kb, vT, hsc, hdir, x2b);
  k_gemm_out<<<dim3(8, 32), 256, 0, stream>>>(x2b, woutT, outp);
}

// Round 10
// 111.157 us; speedup vs baseline: 1.0642x; 1.0642x over previous
//
#include <hip/hip_runtime.h>
#include <stdint.h>

// Problem: B=2, T=2048, C=1024, H=16, HD=64. M = B*T = 4096, 3C = 3072.
// Geo bias folded into Q:  q~[d] = q[d]*SCALE + hs*(q[:8]·dir)*dir[d] (d<8)
// log2(e) additionally folded into Q~ so softmax uses exp2 directly.
// Softmax is MAX-FREE: P = exp2(S') directly (S' provably < ~25 << 127).

typedef float f32x4 __attribute__((ext_vector_type(4)));
typedef unsigned short u16x8 __attribute__((ext_vector_type(8)));
typedef unsigned short u16x4 __attribute__((ext_vector_type(4)));
typedef unsigned int u32x2 __attribute__((ext_vector_type(2)));
typedef __bf16 bf16x8 __attribute__((ext_vector_type(8)));

static __device__ __forceinline__ unsigned short f2bf(float f) {
  unsigned u = __float_as_uint(f);
  u += 0x7FFFu + ((u >> 16) & 1u);
  return (unsigned short)(u >> 16);
}
static __device__ __forceinline__ float bf2f(unsigned short s) {
  return __uint_as_float(((unsigned)s) << 16);
}
static __device__ __forceinline__ f32x4 mfma16(u16x8 a, u16x8 b, f32x4 c) {
  return __builtin_amdgcn_mfma_f32_16x16x32_bf16(
      __builtin_bit_cast(bf16x8, a), __builtin_bit_cast(bf16x8, b), c, 0, 0, 0);
}
static __device__ __forceinline__ unsigned cvtpk(float lo, float hi) {
  unsigned d;
  asm("v_cvt_pk_bf16_f32 %0, %1, %2" : "=v"(d) : "v"(lo), "v"(hi));
  return d;
}

#define GLD16(gp, lp) __builtin_amdgcn_global_load_lds( \
    (const __attribute__((address_space(1))) unsigned int*)(gp), \
    (__attribute__((address_space(3))) unsigned int*)(lp), 16, 0, 0)

// ---------------- fused prep: cast x->bf16 ; transpose+cast wqkv, wout ----------------
__global__ __launch_bounds__(256) void k_prep(const float* __restrict__ x,
                                              const float* __restrict__ wqkv,
                                              const float* __restrict__ wout,
                                              unsigned short* __restrict__ xb,
                                              unsigned short* __restrict__ wqkvT,
                                              unsigned short* __restrict__ woutT) {
  __shared__ float t[64][65];
  const int bid = blockIdx.x;
  if (bid < 4096) {
    int i = bid * 256 + threadIdx.x;
    f32x4 v = *(const f32x4*)(x + (size_t)i * 4);
    u16x4 o;
#pragma unroll
    for (int j = 0; j < 4; ++j) o[j] = f2bf(v[j]);
    *(u16x4*)(xb + (size_t)i * 4) = o;
    return;
  }
  const float* in;
  unsigned short* out;
  int Cc, bx, by;
  if (bid < 4864) {
    int tt = bid - 4096;
    in = wqkv; out = wqkvT; Cc = 3072;
    bx = tt % 48; by = tt / 48;
  } else {
    int tt = bid - 4864;
    in = wout; out = woutT; Cc = 1024;
    bx = tt & 15; by = tt >> 4;
  }
  const int R = 1024;
  int tr = by * 64, tc = bx * 64;
  int tx = threadIdx.x & 15, ty = threadIdx.x >> 4;
#pragma unroll
  for (int i = 0; i < 4; ++i) {
    int rr = ty + i * 16;
    f32x4 v = *(const f32x4*)(in + (size_t)(tr + rr) * Cc + tc + tx * 4);
#pragma unroll
    for (int j = 0; j < 4; ++j) t[rr][tx * 4 + j] = v[j];
  }
  __syncthreads();
#pragma unroll
  for (int i = 0; i < 4; ++i) {
    int cc = ty + i * 16;
    int rr = tx * 4;
    u16x4 o;
#pragma unroll
    for (int j = 0; j < 4; ++j) o[j] = f2bf(t[rr + j][cc]);
    *(u16x4*)(out + (size_t)(tc + cc) * R + tr + rr) = o;
  }
}

// ---------------- GEMM: C[m][n] = sum_k A[m][k] * Bt[n][k]  (K=1024, 128x128 tile, BK=32)
// Proven m97-class structure (R8). R9's 256-ring experiment regressed -> reverted.
template <int MODE>
__global__ __launch_bounds__(256) void k_gemm(const unsigned short* __restrict__ A,
                                              const unsigned short* __restrict__ Bt,
                                              unsigned short* __restrict__ qo,
                                              unsigned short* __restrict__ ko,
                                              unsigned short* __restrict__ vTo,
                                              float* __restrict__ fo) {
  __shared__ unsigned short lA[128 * 32];
  __shared__ unsigned short lB[128 * 32];
  const int tid = threadIdx.x;
  const int lane = tid & 63, wid = tid >> 6;
  const int wr = wid >> 1, wc = wid & 1;
  const int r = lane & 15, g = lane >> 4;
  const int mbase = blockIdx.y * 128;
  const int nbase = blockIdx.x * 128;

  f32x4 acc[4][4] = {};

  for (int kt = 0; kt < 32; ++kt) {
    __syncthreads();
#pragma unroll
    for (int p = 0; p < 2; ++p) {
      int L = p * 4096 + tid * 16;  // byte offset in 8KB tile
      int row = L >> 6;             // 64B per row (32 bf16)
      int blk = (L >> 4) & 3;       // 16B block within row
      GLD16(A + (size_t)(mbase + row) * 1024 + kt * 32 + blk * 8, lA + (L >> 1));
      GLD16(Bt + (size_t)(nbase + row) * 1024 + kt * 32 + blk * 8, lB + (L >> 1));
    }
    __syncthreads();
    u16x8 af[4], bfv[4];
#pragma unroll
    for (int m = 0; m < 4; ++m)
      af[m] = *(const u16x8*)(lA + (wr * 64 + m * 16 + r) * 32 + g * 8);
#pragma unroll
    for (int n = 0; n < 4; ++n)
      bfv[n] = *(const u16x8*)(lB + (wc * 64 + n * 16 + r) * 32 + g * 8);
#pragma unroll
    for (int m = 0; m < 4; ++m)
#pragma unroll
      for (int n = 0; n < 4; ++n) acc[m][n] = mfma16(af[m], bfv[n], acc[m][n]);
  }

#pragma unroll
  for (int m = 0; m < 4; ++m) {
#pragma unroll
    for (int n = 0; n < 4; ++n) {
      int ng = nbase + wc * 64 + n * 16 + r;
      int m0 = mbase + wr * 64 + m * 16 + g * 4;
      if (MODE == 0) {
        int sec = ng >> 10, rem = ng & 1023, hh = rem >> 6, d = rem & 63;
        int b = m0 >> 11, t0 = m0 & 2047;
        size_t bh = (size_t)(b * 16 + hh);
        if (sec == 2) {
          u16x4 o;
#pragma unroll
          for (int e = 0; e < 4; ++e) o[e] = f2bf(acc[m][n][e]);
          *(u16x4*)(vTo + (bh * 64 + d) * 2048 + t0) = o;  // V^T: [bh][d][t]
        } else {
          unsigned short* dst = (sec == 0 ? qo : ko);
#pragma unroll
          for (int e = 0; e < 4; ++e)
            dst[(bh * 2048 + t0 + e) * 64 + d] = f2bf(acc[m][n][e]);
        }
      } else {
#pragma unroll
        for (int e = 0; e < 4; ++e)
          fo[(size_t)(m0 + e) * 1024 + ng] = acc[m][n][e];
      }
    }
  }
}

// ---------------- causal flash attention, head_dim 64, folded E8 bias ----------------
// R5/R8 structure: 1024 blocks x 4 waves, 64 q-rows each, 40KB LDS -> 4 blocks/CU.
// Decode puts a = {j, 31-j, 8+j, 23-j} per CU (work sum 66). Max-free softmax.
// NEW (T3 canonical order): SINGLE barrier per iteration -- STAGE(next) first,
// compute(cur), then vmcnt(0)+s_barrier at iter end. The end barrier both
// publishes tile kt+1 and proves all waves' reads of the overwritten buffer
// retired (every ds_read is consumed by an MFMA before the barrier).
__global__ __launch_bounds__(256) void k_attn(const unsigned short* __restrict__ qb,
                                              const unsigned short* __restrict__ kb,
                                              const unsigned short* __restrict__ vTb,
                                              const float* __restrict__ hsc,
                                              const float* __restrict__ hdir,
                                              unsigned short* __restrict__ o2) {
  __shared__ unsigned short lK[2][64 * 64];   // [buf][kpos][d], XOR-swizzled rows
  __shared__ unsigned short lV[2][64 * 64];   // [buf][d][kpos], XOR-swizzled rows
  __shared__ unsigned short lP[4][16 * 64];   // per-wave P bounce, swizzled

  const int tid = threadIdx.x, lane = tid & 63, wid = tid >> 6;
  const int r = lane & 15, g = lane >> 4;
  const int bid = blockIdx.x;
  const int u = bid & 255, kq = bid >> 8;
  const int bh = u & 31, j = u >> 5;  // j in 0..7
  const int a = (kq == 0) ? j : (kq == 1) ? (31 - j) : (kq == 2) ? (8 + j) : (23 - j);
  const int nk = a + 1;
  const int qbase = a * 64;
  const int h = bh & 15, bi = bh >> 4;

  const size_t kbase = (size_t)bh * (2048 * 64);
  const size_t vbase = (size_t)bh * (64 * 2048);

  auto STAGE = [&](int buf, int kt) {
    unsigned short* dK = (unsigned short*)lK[buf];
    unsigned short* dV = (unsigned short*)lV[buf];
#pragma unroll
    for (int p = 0; p < 2; ++p) {
      int L = p * 4096 + tid * 16;
      int row = L >> 7;           // 128B rows (64 bf16)
      int cb = (L >> 4) & 7;
      int cbg = cb ^ (row & 7);   // pre-swizzled source -> swizzled reads, linear dest
      GLD16(kb + kbase + (size_t)(kt * 64 + row) * 64 + cbg * 8, dK + (L >> 1));
      GLD16(vTb + vbase + (size_t)row * 2048 + kt * 64 + cbg * 8, dV + (L >> 1));
    }
  };

  STAGE(0, 0);  // prologue staging overlaps Q-fragment build

  const float LOG2E = 1.44269504088896f;
  const float hs = hsc[h];
  float dir8[8];
#pragma unroll
  for (int j2 = 0; j2 < 8; ++j2) dir8[j2] = hdir[h * 8 + j2];

  // Folded Q~ fragment (B-operand of swapped QK^T): lane holds Q~[q=r][d-chunk g].
  u16x8 qc0, qc1;
  {
    const unsigned short* qrow = qb + ((size_t)bh * 2048 + qbase + wid * 16 + r) * 64;
    float proj = 0.f;
    u16x8 qv = *(const u16x8*)qrow;
#pragma unroll
    for (int j2 = 0; j2 < 8; ++j2) proj += bf2f(qv[j2]) * dir8[j2];
#pragma unroll
    for (int s = 0; s < 2; ++s) {
      u16x8 raw = *(const u16x8*)(qrow + s * 32 + g * 8);
      u16x8 ov;
#pragma unroll
      for (int j2 = 0; j2 < 8; ++j2) {
        float v = bf2f(raw[j2]) * (0.125f * LOG2E);
        if (s == 0 && g == 0) v += (hs * LOG2E) * proj * dir8[j2];
        ov[j2] = f2bf(v);
      }
      if (s == 0) qc0 = ov; else qc1 = ov;
    }
  }

  f32x4 accO[4] = {};
  float lp = 0.f;   // LANE-PARTIAL denominator (reduced once in epilogue)
  unsigned short* pw = &lP[wid][0];
  const int swz = (r & 7) << 4;
  const int qq = qbase + wid * 16 + r;

  // prologue: tile 0 staged & published
  asm volatile("s_waitcnt vmcnt(0)" ::: "memory");
  __builtin_amdgcn_sched_barrier(0);
  __builtin_amdgcn_s_barrier();

  for (int kt = 0; kt < nk; ++kt) {
    // T3 order: issue next tile's stage FIRST (writes buf[(kt+1)&1], whose
    // last readers retired before the barrier that ended iteration kt-1).
    if (kt + 1 < nk) STAGE((kt + 1) & 1, kt + 1);

    const char* lKc = (const char*)lK[kt & 1];
    const char* lVc = (const char*)lV[kt & 1];

    // S = (K @ Q~^T)^T in log2 domain: lane holds S[q=r][k=ct*16+g*4+e]
    f32x4 accS[4];
    __builtin_amdgcn_s_setprio(1);
#pragma unroll
    for (int ct = 0; ct < 4; ++ct) {
      f32x4 s4 = {0.f, 0.f, 0.f, 0.f};
      int krow = ct * 16 + r;
      int sw = (krow & 7) << 4;
      u16x8 kf0 = *(const u16x8*)(lKc + krow * 128 + ((g * 16) ^ sw));
      u16x8 kf1 = *(const u16x8*)(lKc + krow * 128 + ((64 + g * 16) ^ sw));
      s4 = mfma16(kf0, qc0, s4);
      s4 = mfma16(kf1, qc1, s4);
      accS[ct] = s4;
    }
    __builtin_amdgcn_s_setprio(0);

    if (kt == nk - 1) {  // only the last tile crosses the causal diagonal
#pragma unroll
      for (int ct = 0; ct < 4; ++ct)
#pragma unroll
        for (int e = 0; e < 4; ++e) {
          int kk = kt * 64 + ct * 16 + g * 4 + e;
          if (kk > qq) accS[ct][e] = -1e30f;
        }
    }

    // Max-free softmax: P = exp2(S') straight off the MFMA. No tree/shfl/branch.
    float p[4][4];
#pragma unroll
    for (int ct = 0; ct < 4; ++ct)
#pragma unroll
      for (int e = 0; e < 4; ++e) p[ct][e] = exp2f(accS[ct][e]);
#pragma unroll
    for (int ct = 0; ct < 4; ++ct)
      lp += (p[ct][0] + p[ct][1]) + (p[ct][2] + p[ct][3]);

    // P -> bf16 (cvt_pk) -> per-wave LDS bounce (b64 writes, XOR-swizzled)
#pragma unroll
    for (int ct = 0; ct < 4; ++ct) {
      u32x2 w;
      w[0] = cvtpk(p[ct][0], p[ct][1]);
      w[1] = cvtpk(p[ct][2], p[ct][3]);
      *(u32x2*)((char*)pw + r * 128 + ((ct * 32 + g * 8) ^ swz)) = w;
    }
    asm volatile("s_waitcnt lgkmcnt(0)" ::: "memory");
    __builtin_amdgcn_sched_barrier(0);

    // O^T += V^T @ P^T (swapped): lane gets O[q=r][d=dt*16+g*4+e]
    __builtin_amdgcn_s_setprio(1);
#pragma unroll
    for (int s = 0; s < 2; ++s) {
      u16x8 pa = *(const u16x8*)((const char*)pw + r * 128 + ((s * 64 + g * 16) ^ swz));
#pragma unroll
      for (int dt = 0; dt < 4; ++dt) {
        int dd = dt * 16 + r;
        u16x8 vf = *(const u16x8*)(lVc + dd * 128 + ((s * 64 + g * 16) ^ ((dd & 7) << 4)));
        accO[dt] = mfma16(vf, pa, accO[dt]);
      }
    }
    __builtin_amdgcn_s_setprio(0);

    // single end-of-iter sync: tile kt+1 landed (vmcnt0, was issued before a
    // ~1400cy compute so latency is covered) + all waves' buf reads retired.
    if (kt + 1 < nk) {
      asm volatile("s_waitcnt vmcnt(0)" ::: "memory");
      __builtin_amdgcn_sched_barrier(0);
      __builtin_amdgcn_s_barrier();
    }
  }

  // epilogue: reduce lane-partial l once, then O/l -> bf16 [B,T,C]
  lp += __shfl_xor(lp, 16, 64);
  lp += __shfl_xor(lp, 32, 64);
  float inv = 1.f / lp;
#pragma unroll
  for (int dt = 0; dt < 4; ++dt) {
    u16x4 o;
#pragma unroll
    for (int e = 0; e < 4; ++e) o[e] = f2bf(accO[dt][e] * inv);
    *(u16x4*)(o2 + ((size_t)(bi * 2048 + qq)) * 1024 + h * 64 + dt * 16 + g * 4) = o;
  }
}

extern "C" void kernel_launch(void* const* d_in, const int* in_sizes, int n_in,
                              void* d_out, int out_size, void* d_ws, size_t ws_size,
                              hipStream_t stream) {
  const float* x    = (const float*)d_in[0];
  const float* wqkv = (const float*)d_in[1];
  const float* wout = (const float*)d_in[2];
  const float* hsc  = (const float*)d_in[3];
  const float* hdir = (const float*)d_in[4];
  float* outp = (float*)d_out;

  char* ws = (char*)d_ws;
  unsigned short* xb    = (unsigned short*)(ws + 0);         //  8 MB  [4096][1024]
  unsigned short* wqkvT = (unsigned short*)(ws + 8388608);   //  6 MB  [3072][1024]
  unsigned short* woutT = (unsigned short*)(ws + 14680064);  //  2 MB  [1024][1024]
  unsigned short* qb    = (unsigned short*)(ws + 16777216);  //  8 MB  [32][2048][64]
  unsigned short* kb    = (unsigned short*)(ws + 25165824);  //  8 MB  [32][2048][64]
  unsigned short* vT    = (unsigned short*)(ws + 33554432);  //  8 MB  [32][64][2048]
  unsigned short* x2b   = (unsigned short*)(ws + 41943040);  //  8 MB  [4096][1024]
  if (ws_size < 50331648u) return;

  k_prep<<<5120, 256, 0, stream>>>(x, wqkv, wout, xb, wqkvT, woutT);
  k_gemm<0><<<dim3(24, 32), 256, 0, stream>>>(xb, wqkvT, qb, kb, vT, nullptr);
  k_attn<<<dim3(1024), 256, 0, stream>>>(qb, kb, vT, hsc, hdir, x2b);
  k_gemm<1><<<dim3(8, 32), 256, 0, stream>>>(x2b, woutT, nullptr, nullptr, nullptr, outp);
}